// Round 5
// baseline (2742.922 us; speedup 1.0000x reference)
//
#include <hip/hip_runtime.h>
#include <hip/hip_bf16.h>

typedef __bf16 bf16x8 __attribute__((ext_vector_type(8)));
typedef float  f32x4  __attribute__((ext_vector_type(4)));

// ---------------------------------------------------------------- pack W
// Layout: [li=L*9+i][ks(8)][cf(8)][lane(64)][j(8)]  (bf16)
// k = ks*32 + (lane>>4)*8 + j ; col = cf*16 + (lane&15)
// k < 128 -> W_rel[li][k][col], else W_root[li][k-128][col]
__global__ void __launch_bounds__(256) pack_w(const float* __restrict__ Wrel,
                                              const float* __restrict__ Wroot,
                                              __bf16* __restrict__ Wp)
{
    const int idx = blockIdx.x * 256 + threadIdx.x;
    if (idx >= 2 * 9 * 8 * 8 * 64) return;
    const int lane = idx & 63;
    int t = idx >> 6;
    const int cf = t & 7; t >>= 3;
    const int ks = t & 7; t >>= 3;
    const int li = t;  // 0..17
    const int col = cf * 16 + (lane & 15);
    const int kb  = ks * 32 + (lane >> 4) * 8;
    bf16x8 o;
#pragma unroll
    for (int j = 0; j < 8; ++j) {
        const int k = kb + j;
        const float v = (k < 128)
            ? Wrel [((size_t)li * 128 + k)        * 128 + col]
            : Wroot[((size_t)li * 128 + (k - 128)) * 128 + col];
        o[j] = (__bf16)v;
    }
    *reinterpret_cast<bf16x8*>(Wp + (size_t)idx * 8) = o;
}

// ---------------------------------------------------------------- scatter
// agg(bf16)[dst] += x_src[src]; one wave per edge, one packed-bf16x2 atomic per lane.
__device__ __forceinline__ void pk_atomic(__bf16* p, uint32_t pk)
{
    const uint64_t addr = (uint64_t)p;
    asm volatile("global_atomic_pk_add_bf16 %0, %1, off" :: "v"(addr), "v"(pk) : "memory");
}

__global__ void __launch_bounds__(256) scatter_f32(const float* __restrict__ xsrc,
                                                   const int* __restrict__ ei, int E,
                                                   __bf16* __restrict__ agg)
{
    const int lane = threadIdx.x & 63;
    const int gw = (blockIdx.x * 256 + threadIdx.x) >> 6;
    const int nw = (gridDim.x * 256) >> 6;
    for (int e = gw; e < E; e += nw) {
        const int s = ei[e];
        const int d = ei[E + e];
        const float2 v = *reinterpret_cast<const float2*>(xsrc + (size_t)s * 128 + lane * 2);
        union { __bf16 b[2]; uint32_t u; } cv;
        cv.b[0] = (__bf16)v.x; cv.b[1] = (__bf16)v.y;
        pk_atomic(agg + (size_t)d * 128 + lane * 2, cv.u);
    }
}

__global__ void __launch_bounds__(256) scatter_bf16(const __bf16* __restrict__ xsrc,
                                                    const int* __restrict__ ei, int E,
                                                    __bf16* __restrict__ agg)
{
    const int lane = threadIdx.x & 63;
    const int gw = (blockIdx.x * 256 + threadIdx.x) >> 6;
    const int nw = (gridDim.x * 256) >> 6;
    for (int e = gw; e < E; e += nw) {
        const int s = ei[e];
        const int d = ei[E + e];
        const uint32_t pk = *reinterpret_cast<const uint32_t*>(xsrc + (size_t)s * 128 + lane * 2);
        pk_atomic(agg + (size_t)d * 128 + lane * 2, pk);
    }
}

// ---------------------------------------------------------------- GEMM + BN stats
// h[M,128] = [agg | x_dst](M,256) @ Wp(256,128) + bias ; stats[0:128]=colsum(h), [128:256]=colsum(h^2)
// block = 256 thr (4 waves), tile = 128 rows; wave w owns rows w*32..w*32+31 (2 row-frags),
// all 8 col-frags. 16x16x32 bf16 MFMA. A direct from global, B from packed global (L2).
template<bool XBF16>
__global__ void __launch_bounds__(256) gemm_kernel(const __bf16* __restrict__ agg,
                                                   const void* __restrict__ xdst,
                                                   const __bf16* __restrict__ Wp,
                                                   const float* __restrict__ bias,
                                                   __bf16* __restrict__ hout,
                                                   float* __restrict__ stats, int M)
{
    __shared__ float lsum[128];
    __shared__ float lsq[128];
    const int tid  = threadIdx.x;
    const int lane = tid & 63;
    const int wv   = tid >> 6;
    if (tid < 128) { lsum[tid] = 0.f; lsq[tid] = 0.f; }
    __syncthreads();

    const int r0    = blockIdx.x * 128 + wv * 32;
    const int lrow  = lane & 15;
    const int klane = (lane >> 4) * 8;

    int  car[2]; bool val[2];
#pragma unroll
    for (int rf = 0; rf < 2; ++rf) {
        const int ar = r0 + rf * 16 + lrow;
        val[rf] = ar < M;
        car[rf] = val[rf] ? ar : (M - 1);
    }

    bf16x8 z8;
#pragma unroll
    for (int j = 0; j < 8; ++j) z8[j] = (__bf16)0.f;

    f32x4 acc[2][8];
#pragma unroll
    for (int rf = 0; rf < 2; ++rf)
#pragma unroll
        for (int cf = 0; cf < 8; ++cf) {
            f32x4 z; z[0] = 0.f; z[1] = 0.f; z[2] = 0.f; z[3] = 0.f;
            acc[rf][cf] = z;
        }

    const __bf16* xb = (const __bf16*)xdst;
    const float*  xf = (const float*)xdst;

#pragma unroll
    for (int ks = 0; ks < 8; ++ks) {
        const int koff = (ks & 3) * 32 + klane;
        bf16x8 a[2];
#pragma unroll
        for (int rf = 0; rf < 2; ++rf) {
            if (ks < 4) {
                const bf16x8 av = *reinterpret_cast<const bf16x8*>(
                    agg + (size_t)car[rf] * 128 + koff);
                a[rf] = val[rf] ? av : z8;
            } else if (XBF16) {
                const bf16x8 av = *reinterpret_cast<const bf16x8*>(
                    xb + (size_t)car[rf] * 128 + koff);
                a[rf] = val[rf] ? av : z8;
            } else {
                const float* ap = xf + (size_t)car[rf] * 128 + koff;
                const float4 f0 = *reinterpret_cast<const float4*>(ap);
                const float4 f1 = *reinterpret_cast<const float4*>(ap + 4);
                bf16x8 av;
                av[0] = (__bf16)f0.x; av[1] = (__bf16)f0.y; av[2] = (__bf16)f0.z; av[3] = (__bf16)f0.w;
                av[4] = (__bf16)f1.x; av[5] = (__bf16)f1.y; av[6] = (__bf16)f1.z; av[7] = (__bf16)f1.w;
                a[rf] = val[rf] ? av : z8;
            }
        }
        const bf16x8* wp8 = reinterpret_cast<const bf16x8*>(Wp) + (size_t)ks * 8 * 64 + lane;
        bf16x8 b[8];
#pragma unroll
        for (int cf = 0; cf < 8; ++cf) b[cf] = wp8[(size_t)cf * 64];
#pragma unroll
        for (int rf = 0; rf < 2; ++rf)
#pragma unroll
            for (int cf = 0; cf < 8; ++cf)
                acc[rf][cf] = __builtin_amdgcn_mfma_f32_16x16x32_bf16(a[rf], b[cf], acc[rf][cf], 0, 0, 0);
    }

    float bc[8];
#pragma unroll
    for (int cf = 0; cf < 8; ++cf) bc[cf] = bias[cf * 16 + lrow];

    const int rb = (lane >> 4) * 4;
#pragma unroll
    for (int cf = 0; cf < 8; ++cf) {
        float s = 0.f, q = 0.f;
#pragma unroll
        for (int rf = 0; rf < 2; ++rf) {
#pragma unroll
            for (int rr = 0; rr < 4; ++rr) {
                const int grow = r0 + rf * 16 + rb + rr;
                if (grow < M) {
                    const float hv = acc[rf][cf][rr] + bc[cf];
                    hout[(size_t)grow * 128 + cf * 16 + lrow] = (__bf16)hv;
                    s += hv; q += hv * hv;
                }
            }
        }
        s += __shfl_xor(s, 16); s += __shfl_xor(s, 32);
        q += __shfl_xor(q, 16); q += __shfl_xor(q, 32);
        if (lane < 16) {
            atomicAdd(&lsum[cf * 16 + lane], s);
            atomicAdd(&lsq [cf * 16 + lane], q);
        }
    }
    __syncthreads();
    if (tid < 128) {
        atomicAdd(&stats[tid],       lsum[tid]);
        atomicAdd(&stats[128 + tid], lsq[tid]);
    }
}

// ---------------------------------------------------------------- BN prep
__global__ void prep_kernel(const float* __restrict__ stats,
                            const float* __restrict__ gamma,
                            const float* __restrict__ beta,
                            float* __restrict__ ss, float invM)
{
    const int c = threadIdx.x;
    const float mu   = stats[c] * invM;
    const float var  = stats[128 + c] * invM - mu * mu;
    const float scal = gamma[c] * rsqrtf(var + 1e-5f);
    ss[c]       = scal;
    ss[128 + c] = beta[c] - mu * scal;
}

// ---------------------------------------------------------------- normalize + accumulate
// MODE 0: out(bf16) = v ; MODE 1: out(bf16) += v ; MODE 2: out(f32) += v ;
// MODE 3: out(f32) = resid(f32) + v
template<int MODE>
__global__ void __launch_bounds__(256) norm_kernel(const __bf16* __restrict__ h,
                                                   const float* __restrict__ ss,
                                                   const float* __restrict__ resid,
                                                   void* __restrict__ out, int M)
{
    const int t0   = blockIdx.x * 256 + threadIdx.x;
    const int nthr = gridDim.x * 256;
    const int c0   = (t0 & 15) * 8;
    float sc[8], sh[8];
#pragma unroll
    for (int j = 0; j < 8; ++j) { sc[j] = ss[c0 + j]; sh[j] = ss[128 + c0 + j]; }
    const int nch = M * 16;
    for (int ch = t0; ch < nch; ch += nthr) {
        const bf16x8 hv = *reinterpret_cast<const bf16x8*>(h + (size_t)ch * 8);
        float f[8];
#pragma unroll
        for (int j = 0; j < 8; ++j) f[j] = (float)hv[j] * sc[j] + sh[j];
        if constexpr (MODE == 0) {
            bf16x8 ov;
#pragma unroll
            for (int j = 0; j < 8; ++j) ov[j] = (__bf16)f[j];
            *reinterpret_cast<bf16x8*>((__bf16*)out + (size_t)ch * 8) = ov;
        } else if constexpr (MODE == 1) {
            __bf16* op = (__bf16*)out + (size_t)ch * 8;
            bf16x8 ov = *reinterpret_cast<const bf16x8*>(op);
#pragma unroll
            for (int j = 0; j < 8; ++j) ov[j] = (__bf16)((float)ov[j] + f[j]);
            *reinterpret_cast<bf16x8*>(op) = ov;
        } else if constexpr (MODE == 2) {
            float* op = (float*)out + (size_t)ch * 8;
            float4 o0 = *reinterpret_cast<float4*>(op);
            float4 o1 = *reinterpret_cast<float4*>(op + 4);
            o0.x += f[0]; o0.y += f[1]; o0.z += f[2]; o0.w += f[3];
            o1.x += f[4]; o1.y += f[5]; o1.z += f[6]; o1.w += f[7];
            *reinterpret_cast<float4*>(op)     = o0;
            *reinterpret_cast<float4*>(op + 4) = o1;
        } else {
            const float* rp = resid + (size_t)ch * 8;
            const float4 r0 = *reinterpret_cast<const float4*>(rp);
            const float4 r1 = *reinterpret_cast<const float4*>(rp + 4);
            float* op = (float*)out + (size_t)ch * 8;
            float4 o0, o1;
            o0.x = r0.x + f[0]; o0.y = r0.y + f[1]; o0.z = r0.z + f[2]; o0.w = r0.w + f[3];
            o1.x = r1.x + f[4]; o1.y = r1.y + f[5]; o1.z = r1.z + f[6]; o1.w = r1.w + f[7];
            *reinterpret_cast<float4*>(op)     = o0;
            *reinterpret_cast<float4*>(op + 4) = o1;
        }
    }
}

// ---------------------------------------------------------------- launch
extern "C" void kernel_launch(void* const* d_in, const int* in_sizes, int n_in,
                              void* d_out, int out_size, void* d_ws, size_t ws_size,
                              hipStream_t stream)
{
    const float* xin[3] = {(const float*)d_in[0], (const float*)d_in[1], (const float*)d_in[2]};
    const int N[3] = {in_sizes[0] / 128, in_sizes[1] / 128, in_sizes[2] / 128};
    const float* Wrel  = (const float*)d_in[12];
    const float* brel  = (const float*)d_in[13];
    const float* Wroot = (const float*)d_in[14];
    const float* gamma = (const float*)d_in[15];
    const float* beta  = (const float*)d_in[16];

    // ETS order: a2b b2a a2g g2a b2g g2b a2a b2b g2g  (atom=0,bond=1,global=2)
    const int cs[9] = {0, 1, 0, 2, 1, 2, 0, 1, 2};
    const int cd[9] = {1, 0, 2, 0, 2, 1, 0, 1, 2};

    const size_t nA = (size_t)N[0] * 128, nB = (size_t)N[1] * 128, nG = (size_t)N[2] * 128;
    const size_t off[3] = {0, nA, nA + nB};
    const size_t xtot = nA + nB + nG;
    size_t maxN = (size_t)N[0];
    if ((size_t)N[1] > maxN) maxN = N[1];
    if ((size_t)N[2] > maxN) maxN = N[2];

    // ws layout (~207 MB): x1(bf16) | agg(bf16,maxN) | h(bf16,maxN) | stats(18 slots) | ss(18) | Wp
    char* w = (char*)d_ws;
    __bf16* x1    = (__bf16*)w;  w += xtot * 2;
    __bf16* agg   = (__bf16*)w;  w += maxN * 128 * 2;
    __bf16* hbuf  = (__bf16*)w;  w += maxN * 128 * 2;
    float*  stats = (float*)w;   w += 18 * 256 * 4;
    float*  ss    = (float*)w;   w += 18 * 256 * 4;
    __bf16* Wp    = (__bf16*)w;
    (void)ws_size; (void)n_in; (void)out_size;

    pack_w<<<288, 256, 0, stream>>>(Wrel, Wroot, Wp);
    hipMemsetAsync(stats, 0, 18 * 256 * 4, stream);

    float* dout = (float*)d_out;

    for (int L = 0; L < 2; ++L) {
        for (int i = 0; i < 9; ++i) {
            const int s = cs[i], d = cd[i];
            const int E = in_sizes[3 + i] / 2;
            const int* ei = (const int*)d_in[3 + i];
            const int li = L * 9 + i;
            float* st = stats + li * 256;
            float* sl = ss + li * 256;

            hipMemsetAsync(agg, 0, (size_t)N[d] * 128 * 2, stream);
            int sb = (E + 3) / 4; if (sb > 2048) sb = 2048; if (sb < 1) sb = 1;
            if (L == 0) scatter_f32 <<<sb, 256, 0, stream>>>(xin[s], ei, E, agg);
            else        scatter_bf16<<<sb, 256, 0, stream>>>(x1 + off[s], ei, E, agg);

            const int gb = (N[d] + 127) / 128;
            if (L == 0)
                gemm_kernel<false><<<gb, 256, 0, stream>>>(agg, (const void*)xin[d],
                    Wp + (size_t)li * 32768, brel + li * 128, hbuf, st, N[d]);
            else
                gemm_kernel<true ><<<gb, 256, 0, stream>>>(agg, (const void*)(x1 + off[d]),
                    Wp + (size_t)li * 32768, brel + li * 128, hbuf, st, N[d]);

            prep_kernel<<<1, 128, 0, stream>>>(st, gamma + li * 128, beta + li * 128,
                                               sl, 1.0f / (float)N[d]);

            const long long nch = (long long)N[d] * 16;
            int nb = (int)((nch + 255) / 256); if (nb > 2048) nb = 2048;
            if (L == 0) {
                if (i < 3) norm_kernel<0><<<nb, 256, 0, stream>>>(hbuf, sl, nullptr, (void*)(x1 + off[d]), N[d]);
                else       norm_kernel<1><<<nb, 256, 0, stream>>>(hbuf, sl, nullptr, (void*)(x1 + off[d]), N[d]);
            } else {
                if (i < 3) norm_kernel<3><<<nb, 256, 0, stream>>>(hbuf, sl, xin[d], (void*)(dout + off[d]), N[d]);
                else       norm_kernel<2><<<nb, 256, 0, stream>>>(hbuf, sl, nullptr, (void*)(dout + off[d]), N[d]);
            }
        }
    }
}

// Round 6
// 2311.687 us; speedup vs baseline: 1.1865x; 1.1865x over previous
//
#include <hip/hip_runtime.h>
#include <hip/hip_bf16.h>

typedef __bf16 bf16x8 __attribute__((ext_vector_type(8)));
typedef float  f32x4  __attribute__((ext_vector_type(4)));

#define SCHUNK 2048  // elements per scan1 block (256 thr * 8)

struct EdgeArgs {
    const int* ei[9];
    int E[9];
    int ebase[10];   // prefix over edges
    int binbase[9];  // prefix over dst bins
};

// ---------------------------------------------------------------- pack W
// Layout: [li=L*9+i][ks(8)][cf(8)][lane(64)][j(8)]  (bf16)
// k = ks*32 + (lane>>4)*8 + j ; col = cf*16 + (lane&15)
__global__ void __launch_bounds__(256) pack_w(const float* __restrict__ Wrel,
                                              const float* __restrict__ Wroot,
                                              __bf16* __restrict__ Wp)
{
    const int idx = blockIdx.x * 256 + threadIdx.x;
    if (idx >= 2 * 9 * 8 * 8 * 64) return;
    const int lane = idx & 63;
    int t = idx >> 6;
    const int cf = t & 7; t >>= 3;
    const int ks = t & 7; t >>= 3;
    const int li = t;  // 0..17
    const int col = cf * 16 + (lane & 15);
    const int kb  = ks * 32 + (lane >> 4) * 8;
    bf16x8 o;
#pragma unroll
    for (int j = 0; j < 8; ++j) {
        const int k = kb + j;
        const float v = (k < 128)
            ? Wrel [((size_t)li * 128 + k)        * 128 + col]
            : Wroot[((size_t)li * 128 + (k - 128)) * 128 + col];
        o[j] = (__bf16)v;
    }
    *reinterpret_cast<bf16x8*>(Wp + (size_t)idx * 8) = o;
}

// ---------------------------------------------------------------- f32 -> bf16 convert
__global__ void __launch_bounds__(256) cvt_kernel(const float* __restrict__ in,
                                                  __bf16* __restrict__ out, int n8)
{
    int i = blockIdx.x * 256 + threadIdx.x;
    const int stride = gridDim.x * 256;
    for (; i < n8; i += stride) {
        const float4 f0 = *reinterpret_cast<const float4*>(in + (size_t)i * 8);
        const float4 f1 = *reinterpret_cast<const float4*>(in + (size_t)i * 8 + 4);
        bf16x8 o;
        o[0] = (__bf16)f0.x; o[1] = (__bf16)f0.y; o[2] = (__bf16)f0.z; o[3] = (__bf16)f0.w;
        o[4] = (__bf16)f1.x; o[5] = (__bf16)f1.y; o[6] = (__bf16)f1.z; o[7] = (__bf16)f1.w;
        *reinterpret_cast<bf16x8*>(out + (size_t)i * 8) = o;
    }
}

// ---------------------------------------------------------------- CSR build
__global__ void __launch_bounds__(256) hist_kernel(EdgeArgs ea, int Etot,
                                                   int* __restrict__ deg)
{
    int g = blockIdx.x * 256 + threadIdx.x;
    const int stride = gridDim.x * 256;
    for (; g < Etot; g += stride) {
        int t = 0;
        while (g >= ea.ebase[t + 1]) ++t;
        const int e = g - ea.ebase[t];
        const int dst = ea.ei[t][ea.E[t] + e];
        atomicAdd(&deg[ea.binbase[t] + dst], 1);
    }
}

__global__ void __launch_bounds__(256) scan1_kernel(const int* __restrict__ deg, int n,
                                                    int* __restrict__ rowptr,
                                                    int* __restrict__ bsum)
{
    __shared__ int lds[256];
    const int tid = threadIdx.x;
    const int base = blockIdx.x * SCHUNK + tid * 8;
    int v[8]; int tsum = 0;
#pragma unroll
    for (int j = 0; j < 8; ++j) { v[j] = (base + j < n) ? deg[base + j] : 0; tsum += v[j]; }
    int incl = tsum;
    lds[tid] = incl; __syncthreads();
    for (int off = 1; off < 256; off <<= 1) {
        const int add = (tid >= off) ? lds[tid - off] : 0;
        __syncthreads();
        incl += add; lds[tid] = incl; __syncthreads();
    }
    if (tid == 255) bsum[blockIdx.x] = incl;
    int run = incl - tsum;
#pragma unroll
    for (int j = 0; j < 8; ++j) { if (base + j < n) rowptr[base + j] = run; run += v[j]; }
}

__global__ void __launch_bounds__(256) scan2_kernel(int* __restrict__ bsum, int nb)
{
    __shared__ int lds[256];
    __shared__ int carry_s;
    const int tid = threadIdx.x;
    if (tid == 0) carry_s = 0;
    __syncthreads();
    for (int base = 0; base < nb; base += 256) {
        const int v = (base + tid < nb) ? bsum[base + tid] : 0;
        int incl = v;
        lds[tid] = incl; __syncthreads();
        for (int off = 1; off < 256; off <<= 1) {
            const int add = (tid >= off) ? lds[tid - off] : 0;
            __syncthreads();
            incl += add; lds[tid] = incl; __syncthreads();
        }
        const int total = lds[255];
        const int carry = carry_s;
        if (base + tid < nb) bsum[base + tid] = incl - v + carry;
        __syncthreads();
        if (tid == 0) carry_s = carry + total;
        __syncthreads();
    }
}

__global__ void __launch_bounds__(256) fixup_kernel(int* __restrict__ rowptr,
                                                    const int* __restrict__ bsum, int n,
                                                    int Etot, int* __restrict__ cursor)
{
    int i = blockIdx.x * 256 + threadIdx.x;
    const int stride = gridDim.x * 256;
    if (i == 0) rowptr[n] = Etot;
    for (; i < n; i += stride) {
        const int r = rowptr[i] + bsum[i >> 11];
        rowptr[i] = r; cursor[i] = r;
    }
}

__global__ void __launch_bounds__(256) place_kernel(EdgeArgs ea, int Etot,
                                                    int* __restrict__ cursor,
                                                    int* __restrict__ csr)
{
    int g = blockIdx.x * 256 + threadIdx.x;
    const int stride = gridDim.x * 256;
    for (; g < Etot; g += stride) {
        int t = 0;
        while (g >= ea.ebase[t + 1]) ++t;
        const int e = g - ea.ebase[t];
        const int src = ea.ei[t][e];
        const int dst = ea.ei[t][ea.E[t] + e];
        const int pos = atomicAdd(&cursor[ea.binbase[t] + dst], 1);
        csr[pos] = src;
    }
}

// ---------------------------------------------------------------- gather (CSR sum)
// 16-lane group per dst row; fp32 register accumulate; single coalesced write.
__global__ void __launch_bounds__(256) gather16(const __bf16* __restrict__ x,
                                                const int* __restrict__ rowptr,
                                                const int* __restrict__ csr,
                                                __bf16* __restrict__ agg, int N)
{
    const int l16 = threadIdx.x & 15;
    int g = (blockIdx.x * 256 + threadIdx.x) >> 4;
    const int ng = (gridDim.x * 256) >> 4;
    for (int row = g; row < N; row += ng) {
        const int p0 = rowptr[row], p1 = rowptr[row + 1];
        float acc[8] = {0.f, 0.f, 0.f, 0.f, 0.f, 0.f, 0.f, 0.f};
        for (int p = p0; p < p1; ++p) {
            const int s = csr[p];
            const bf16x8 v = *reinterpret_cast<const bf16x8*>(x + (size_t)s * 128 + l16 * 8);
#pragma unroll
            for (int j = 0; j < 8; ++j) acc[j] += (float)v[j];
        }
        bf16x8 o;
#pragma unroll
        for (int j = 0; j < 8; ++j) o[j] = (__bf16)acc[j];
        *reinterpret_cast<bf16x8*>(agg + (size_t)row * 128 + l16 * 8) = o;
    }
}

// wave per dst row (high-degree rows, e.g. dst=global): 4 edges in flight.
__global__ void __launch_bounds__(256) gather64(const __bf16* __restrict__ x,
                                                const int* __restrict__ rowptr,
                                                const int* __restrict__ csr,
                                                __bf16* __restrict__ agg, int N)
{
    const int lane = threadIdx.x & 63;
    const int l16 = lane & 15, grp = lane >> 4;
    int wv = (blockIdx.x * 256 + threadIdx.x) >> 6;
    const int nwv = (gridDim.x * 256) >> 6;
    for (int row = wv; row < N; row += nwv) {
        const int p0 = rowptr[row], p1 = rowptr[row + 1];
        float acc[8] = {0.f, 0.f, 0.f, 0.f, 0.f, 0.f, 0.f, 0.f};
        for (int p = p0 + grp; p < p1; p += 4) {
            const int s = csr[p];
            const bf16x8 v = *reinterpret_cast<const bf16x8*>(x + (size_t)s * 128 + l16 * 8);
#pragma unroll
            for (int j = 0; j < 8; ++j) acc[j] += (float)v[j];
        }
#pragma unroll
        for (int j = 0; j < 8; ++j) {
            acc[j] += __shfl_xor(acc[j], 16);
            acc[j] += __shfl_xor(acc[j], 32);
        }
        if (grp == 0) {
            bf16x8 o;
#pragma unroll
            for (int j = 0; j < 8; ++j) o[j] = (__bf16)acc[j];
            *reinterpret_cast<bf16x8*>(agg + (size_t)row * 128 + l16 * 8) = o;
        }
    }
}

// ---------------------------------------------------------------- GEMM + BN stats
// h[M,128] = [agg | x_dst](M,256) @ Wp(256,128) + bias ; stats += {colsum(h), colsum(h^2)}
__global__ void __launch_bounds__(256) gemm_kernel(const __bf16* __restrict__ agg,
                                                   const __bf16* __restrict__ xb,
                                                   const __bf16* __restrict__ Wp,
                                                   const float* __restrict__ bias,
                                                   __bf16* __restrict__ hout,
                                                   float* __restrict__ stats, int M)
{
    __shared__ float lsum[128];
    __shared__ float lsq[128];
    const int tid  = threadIdx.x;
    const int lane = tid & 63;
    const int wv   = tid >> 6;
    if (tid < 128) { lsum[tid] = 0.f; lsq[tid] = 0.f; }
    __syncthreads();

    const int r0    = blockIdx.x * 128 + wv * 32;
    const int lrow  = lane & 15;
    const int klane = (lane >> 4) * 8;

    int  car[2]; bool val[2];
#pragma unroll
    for (int rf = 0; rf < 2; ++rf) {
        const int ar = r0 + rf * 16 + lrow;
        val[rf] = ar < M;
        car[rf] = val[rf] ? ar : (M - 1);
    }

    bf16x8 z8;
#pragma unroll
    for (int j = 0; j < 8; ++j) z8[j] = (__bf16)0.f;

    f32x4 acc[2][8];
#pragma unroll
    for (int rf = 0; rf < 2; ++rf)
#pragma unroll
        for (int cf = 0; cf < 8; ++cf) {
            f32x4 z; z[0] = 0.f; z[1] = 0.f; z[2] = 0.f; z[3] = 0.f;
            acc[rf][cf] = z;
        }

#pragma unroll
    for (int ks = 0; ks < 8; ++ks) {
        const int koff = (ks & 3) * 32 + klane;
        const __bf16* asrc = (ks < 4) ? agg : xb;
        bf16x8 a[2];
#pragma unroll
        for (int rf = 0; rf < 2; ++rf) {
            const bf16x8 av = *reinterpret_cast<const bf16x8*>(
                asrc + (size_t)car[rf] * 128 + koff);
            a[rf] = val[rf] ? av : z8;
        }
        const bf16x8* wp8 = reinterpret_cast<const bf16x8*>(Wp) + (size_t)ks * 8 * 64 + lane;
        bf16x8 b[8];
#pragma unroll
        for (int cf = 0; cf < 8; ++cf) b[cf] = wp8[(size_t)cf * 64];
#pragma unroll
        for (int rf = 0; rf < 2; ++rf)
#pragma unroll
            for (int cf = 0; cf < 8; ++cf)
                acc[rf][cf] = __builtin_amdgcn_mfma_f32_16x16x32_bf16(a[rf], b[cf], acc[rf][cf], 0, 0, 0);
    }

    float bc[8];
#pragma unroll
    for (int cf = 0; cf < 8; ++cf) bc[cf] = bias[cf * 16 + lrow];

    const int rb = (lane >> 4) * 4;
#pragma unroll
    for (int cf = 0; cf < 8; ++cf) {
        float s = 0.f, q = 0.f;
#pragma unroll
        for (int rf = 0; rf < 2; ++rf) {
#pragma unroll
            for (int rr = 0; rr < 4; ++rr) {
                const int grow = r0 + rf * 16 + rb + rr;
                if (grow < M) {
                    const float hv = acc[rf][cf][rr] + bc[cf];
                    hout[(size_t)grow * 128 + cf * 16 + lrow] = (__bf16)hv;
                    s += hv; q += hv * hv;
                }
            }
        }
        s += __shfl_xor(s, 16); s += __shfl_xor(s, 32);
        q += __shfl_xor(q, 16); q += __shfl_xor(q, 32);
        if (lane < 16) {
            atomicAdd(&lsum[cf * 16 + lane], s);
            atomicAdd(&lsq [cf * 16 + lane], q);
        }
    }
    __syncthreads();
    if (tid < 128) {
        atomicAdd(&stats[tid],       lsum[tid]);
        atomicAdd(&stats[128 + tid], lsq[tid]);
    }
}

// ---------------------------------------------------------------- normalize + accumulate
// BN prep folded in: each block derives scale/shift from stats in LDS.
// MODE 0: out(bf16)=v ; 1: out(bf16)+=v ; 2: out(f32)+=v ; 3: out(f32)=resid+v
template<int MODE>
__global__ void __launch_bounds__(256) norm_kernel(const __bf16* __restrict__ h,
                                                   const float* __restrict__ stats,
                                                   const float* __restrict__ gamma,
                                                   const float* __restrict__ beta,
                                                   float invM,
                                                   const float* __restrict__ resid,
                                                   void* __restrict__ out, int M)
{
    __shared__ float ssc[128], ssh[128];
    const int tid = threadIdx.x;
    if (tid < 128) {
        const float mu   = stats[tid] * invM;
        const float var  = stats[128 + tid] * invM - mu * mu;
        const float scal = gamma[tid] * rsqrtf(var + 1e-5f);
        ssc[tid] = scal;
        ssh[tid] = beta[tid] - mu * scal;
    }
    __syncthreads();

    const int t0   = blockIdx.x * 256 + tid;
    const int nthr = gridDim.x * 256;
    const int c0   = (t0 & 15) * 8;
    float sc[8], sh[8];
#pragma unroll
    for (int j = 0; j < 8; ++j) { sc[j] = ssc[c0 + j]; sh[j] = ssh[c0 + j]; }
    const int nch = M * 16;
    for (int ch = t0; ch < nch; ch += nthr) {
        const bf16x8 hv = *reinterpret_cast<const bf16x8*>(h + (size_t)ch * 8);
        float f[8];
#pragma unroll
        for (int j = 0; j < 8; ++j) f[j] = (float)hv[j] * sc[j] + sh[j];
        if constexpr (MODE == 0) {
            bf16x8 ov;
#pragma unroll
            for (int j = 0; j < 8; ++j) ov[j] = (__bf16)f[j];
            *reinterpret_cast<bf16x8*>((__bf16*)out + (size_t)ch * 8) = ov;
        } else if constexpr (MODE == 1) {
            __bf16* op = (__bf16*)out + (size_t)ch * 8;
            bf16x8 ov = *reinterpret_cast<const bf16x8*>(op);
#pragma unroll
            for (int j = 0; j < 8; ++j) ov[j] = (__bf16)((float)ov[j] + f[j]);
            *reinterpret_cast<bf16x8*>(op) = ov;
        } else if constexpr (MODE == 2) {
            float* op = (float*)out + (size_t)ch * 8;
            float4 o0 = *reinterpret_cast<float4*>(op);
            float4 o1 = *reinterpret_cast<float4*>(op + 4);
            o0.x += f[0]; o0.y += f[1]; o0.z += f[2]; o0.w += f[3];
            o1.x += f[4]; o1.y += f[5]; o1.z += f[6]; o1.w += f[7];
            *reinterpret_cast<float4*>(op)     = o0;
            *reinterpret_cast<float4*>(op + 4) = o1;
        } else {
            const float* rp = resid + (size_t)ch * 8;
            const float4 r0 = *reinterpret_cast<const float4*>(rp);
            const float4 r1 = *reinterpret_cast<const float4*>(rp + 4);
            float* op = (float*)out + (size_t)ch * 8;
            float4 o0, o1;
            o0.x = r0.x + f[0]; o0.y = r0.y + f[1]; o0.z = r0.z + f[2]; o0.w = r0.w + f[3];
            o1.x = r1.x + f[4]; o1.y = r1.y + f[5]; o1.z = r1.z + f[6]; o1.w = r1.w + f[7];
            *reinterpret_cast<float4*>(op)     = o0;
            *reinterpret_cast<float4*>(op + 4) = o1;
        }
    }
}

// ---------------------------------------------------------------- launch
extern "C" void kernel_launch(void* const* d_in, const int* in_sizes, int n_in,
                              void* d_out, int out_size, void* d_ws, size_t ws_size,
                              hipStream_t stream)
{
    const float* xin[3] = {(const float*)d_in[0], (const float*)d_in[1], (const float*)d_in[2]};
    const int N[3] = {in_sizes[0] / 128, in_sizes[1] / 128, in_sizes[2] / 128};
    const float* Wrel  = (const float*)d_in[12];
    const float* brel  = (const float*)d_in[13];
    const float* Wroot = (const float*)d_in[14];
    const float* gamma = (const float*)d_in[15];
    const float* beta  = (const float*)d_in[16];

    // ETS order: a2b b2a a2g g2a b2g g2b a2a b2b g2g  (atom=0,bond=1,global=2)
    const int cs[9] = {0, 1, 0, 2, 1, 2, 0, 1, 2};
    const int cd[9] = {1, 0, 2, 0, 2, 1, 0, 1, 2};

    const size_t nA = (size_t)N[0] * 128, nB = (size_t)N[1] * 128, nG = (size_t)N[2] * 128;
    const size_t off[3] = {0, nA, nA + nB};
    const size_t xtot = nA + nB + nG;
    size_t maxN = (size_t)N[0];
    if ((size_t)N[1] > maxN) maxN = N[1];
    if ((size_t)N[2] > maxN) maxN = N[2];

    // edge/bin geometry
    EdgeArgs ea;
    int Etot = 0, Nbins = 0;
    ea.ebase[0] = 0;
    for (int t = 0; t < 9; ++t) {
        ea.ei[t] = (const int*)d_in[3 + t];
        ea.E[t]  = in_sizes[3 + t] / 2;
        ea.ebase[t + 1] = ea.ebase[t] + ea.E[t];
        ea.binbase[t] = Nbins;
        Nbins += N[cd[t]];
    }
    Etot = ea.ebase[9];
    const int nb1 = (Nbins + SCHUNK - 1) / SCHUNK;

    // ws layout (~335 MB)
    auto al = [](size_t x) { return (x + 15) & ~(size_t)15; };
    char* w = (char*)d_ws;
    __bf16* x0b   = (__bf16*)w;  w += al(xtot * 2);
    __bf16* x1    = (__bf16*)w;  w += al(xtot * 2);
    __bf16* agg   = (__bf16*)w;  w += al(maxN * 128 * 2);
    __bf16* hbuf  = (__bf16*)w;  w += al(maxN * 128 * 2);
    float*  stats = (float*)w;   w += al(18 * 256 * 4);
    __bf16* Wp    = (__bf16*)w;  w += al((size_t)18 * 32768 * 2);
    int*    deg   = (int*)w;     w += al((size_t)Nbins * 4);
    int*    rowptr= (int*)w;     w += al(((size_t)Nbins + 1) * 4);
    int*    cursor= (int*)w;     w += al((size_t)Nbins * 4);
    int*    csr   = (int*)w;     w += al((size_t)Etot * 4);
    int*    bsum  = (int*)w;     w += al((size_t)nb1 * 4);
    (void)ws_size; (void)n_in; (void)out_size;

    pack_w<<<288, 256, 0, stream>>>(Wrel, Wroot, Wp);
    for (int k = 0; k < 3; ++k) {
        const int n8 = (int)(((k == 0 ? nA : k == 1 ? nB : nG)) / 8);
        int cb = (n8 + 255) / 256; if (cb > 2048) cb = 2048;
        cvt_kernel<<<cb, 256, 0, stream>>>(xin[k], x0b + off[k], n8);
    }
    hipMemsetAsync(deg, 0, (size_t)Nbins * 4, stream);
    hipMemsetAsync(stats, 0, 18 * 256 * 4, stream);

    int eb = (Etot + 255) / 256; if (eb > 2048) eb = 2048;
    hist_kernel<<<eb, 256, 0, stream>>>(ea, Etot, deg);
    scan1_kernel<<<nb1, 256, 0, stream>>>(deg, Nbins, rowptr, bsum);
    scan2_kernel<<<1, 256, 0, stream>>>(bsum, nb1);
    int fb = (Nbins + 255) / 256; if (fb > 2048) fb = 2048;
    fixup_kernel<<<fb, 256, 0, stream>>>(rowptr, bsum, Nbins, Etot, cursor);
    place_kernel<<<eb, 256, 0, stream>>>(ea, Etot, cursor, csr);

    float* dout = (float*)d_out;

    for (int L = 0; L < 2; ++L) {
        const __bf16* xsrcbase = (L == 0) ? x0b : x1;
        for (int i = 0; i < 9; ++i) {
            const int s = cs[i], d = cd[i];
            const int E = ea.E[i];
            const int li = L * 9 + i;
            float* st = stats + li * 256;
            const int Nd = N[d];

            const int* rp = rowptr + ea.binbase[i];
            if (E >= 8 * Nd) {  // high-degree rows: wave per row
                int gb2 = (Nd * 64 + 255) / 256; if (gb2 > 2048) gb2 = 2048; if (gb2 < 1) gb2 = 1;
                gather64<<<gb2, 256, 0, stream>>>(xsrcbase + off[s], rp, csr, agg, Nd);
            } else {
                int gb2 = (Nd * 16 + 255) / 256; if (gb2 > 2048) gb2 = 2048; if (gb2 < 1) gb2 = 1;
                gather16<<<gb2, 256, 0, stream>>>(xsrcbase + off[s], rp, csr, agg, Nd);
            }

            const int gb = (Nd + 127) / 128;
            gemm_kernel<<<gb, 256, 0, stream>>>(agg, xsrcbase + off[d],
                Wp + (size_t)li * 32768, brel + li * 128, hbuf, st, Nd);

            const float invM = 1.0f / (float)Nd;
            const long long nch = (long long)Nd * 16;
            int nb = (int)((nch + 255) / 256); if (nb > 2048) nb = 2048;
            if (L == 0) {
                if (i < 3) norm_kernel<0><<<nb, 256, 0, stream>>>(hbuf, st, gamma + li * 128,
                               beta + li * 128, invM, nullptr, (void*)(x1 + off[d]), Nd);
                else       norm_kernel<1><<<nb, 256, 0, stream>>>(hbuf, st, gamma + li * 128,
                               beta + li * 128, invM, nullptr, (void*)(x1 + off[d]), Nd);
            } else {
                if (i < 3) norm_kernel<3><<<nb, 256, 0, stream>>>(hbuf, st, gamma + li * 128,
                               beta + li * 128, invM, xin[d], (void*)(dout + off[d]), Nd);
                else       norm_kernel<2><<<nb, 256, 0, stream>>>(hbuf, st, gamma + li * 128,
                               beta + li * 128, invM, nullptr, (void*)(dout + off[d]), Nd);
            }
        }
    }
}

// Round 7
// 2279.498 us; speedup vs baseline: 1.2033x; 1.0141x over previous
//
#include <hip/hip_runtime.h>
#include <hip/hip_bf16.h>

typedef __bf16 bf16x8 __attribute__((ext_vector_type(8)));
typedef float  f32x4  __attribute__((ext_vector_type(4)));

#define SCHUNK 2048  // elements per scan1 block (256 thr * 8)

struct EdgeArgs {
    const int* ei[9];
    int E[9];
    int ebase[10];   // prefix over edges
    int binbase[9];  // prefix over dst bins
};

// ---------------------------------------------------------------- pack W
// Layout: [li=L*9+i][ks(8)][cf(8)][lane(64)][j(8)]  (bf16)
// k = ks*32 + (lane>>4)*8 + j ; col = cf*16 + (lane&15)
__global__ void __launch_bounds__(256) pack_w(const float* __restrict__ Wrel,
                                              const float* __restrict__ Wroot,
                                              __bf16* __restrict__ Wp)
{
    const int idx = blockIdx.x * 256 + threadIdx.x;
    if (idx >= 2 * 9 * 8 * 8 * 64) return;
    const int lane = idx & 63;
    int t = idx >> 6;
    const int cf = t & 7; t >>= 3;
    const int ks = t & 7; t >>= 3;
    const int li = t;  // 0..17
    const int col = cf * 16 + (lane & 15);
    const int kb  = ks * 32 + (lane >> 4) * 8;
    bf16x8 o;
#pragma unroll
    for (int j = 0; j < 8; ++j) {
        const int k = kb + j;
        const float v = (k < 128)
            ? Wrel [((size_t)li * 128 + k)        * 128 + col]
            : Wroot[((size_t)li * 128 + (k - 128)) * 128 + col];
        o[j] = (__bf16)v;
    }
    *reinterpret_cast<bf16x8*>(Wp + (size_t)idx * 8) = o;
}

// ---------------------------------------------------------------- f32 -> bf16 convert
__global__ void __launch_bounds__(256) cvt_kernel(const float* __restrict__ in,
                                                  __bf16* __restrict__ out, int n8)
{
    int i = blockIdx.x * 256 + threadIdx.x;
    const int stride = gridDim.x * 256;
    for (; i < n8; i += stride) {
        const float4 f0 = *reinterpret_cast<const float4*>(in + (size_t)i * 8);
        const float4 f1 = *reinterpret_cast<const float4*>(in + (size_t)i * 8 + 4);
        bf16x8 o;
        o[0] = (__bf16)f0.x; o[1] = (__bf16)f0.y; o[2] = (__bf16)f0.z; o[3] = (__bf16)f0.w;
        o[4] = (__bf16)f1.x; o[5] = (__bf16)f1.y; o[6] = (__bf16)f1.z; o[7] = (__bf16)f1.w;
        *reinterpret_cast<bf16x8*>(out + (size_t)i * 8) = o;
    }
}

// ---------------------------------------------------------------- CSR build
__global__ void __launch_bounds__(256) hist_kernel(EdgeArgs ea, int Etot,
                                                   int* __restrict__ deg)
{
    int g = blockIdx.x * 256 + threadIdx.x;
    const int stride = gridDim.x * 256;
    for (; g < Etot; g += stride) {
        int t = 0;
        while (g >= ea.ebase[t + 1]) ++t;
        const int e = g - ea.ebase[t];
        const int dst = ea.ei[t][ea.E[t] + e];
        atomicAdd(&deg[ea.binbase[t] + dst], 1);
    }
}

__global__ void __launch_bounds__(256) scan1_kernel(const int* __restrict__ deg, int n,
                                                    int* __restrict__ rowptr,
                                                    int* __restrict__ bsum)
{
    __shared__ int lds[256];
    const int tid = threadIdx.x;
    const int base = blockIdx.x * SCHUNK + tid * 8;
    int v[8]; int tsum = 0;
#pragma unroll
    for (int j = 0; j < 8; ++j) { v[j] = (base + j < n) ? deg[base + j] : 0; tsum += v[j]; }
    int incl = tsum;
    lds[tid] = incl; __syncthreads();
    for (int off = 1; off < 256; off <<= 1) {
        const int add = (tid >= off) ? lds[tid - off] : 0;
        __syncthreads();
        incl += add; lds[tid] = incl; __syncthreads();
    }
    if (tid == 255) bsum[blockIdx.x] = incl;
    int run = incl - tsum;
#pragma unroll
    for (int j = 0; j < 8; ++j) { if (base + j < n) rowptr[base + j] = run; run += v[j]; }
}

__global__ void __launch_bounds__(256) scan2_kernel(int* __restrict__ bsum, int nb)
{
    __shared__ int lds[256];
    __shared__ int carry_s;
    const int tid = threadIdx.x;
    if (tid == 0) carry_s = 0;
    __syncthreads();
    for (int base = 0; base < nb; base += 256) {
        const int v = (base + tid < nb) ? bsum[base + tid] : 0;
        int incl = v;
        lds[tid] = incl; __syncthreads();
        for (int off = 1; off < 256; off <<= 1) {
            const int add = (tid >= off) ? lds[tid - off] : 0;
            __syncthreads();
            incl += add; lds[tid] = incl; __syncthreads();
        }
        const int total = lds[255];
        const int carry = carry_s;
        if (base + tid < nb) bsum[base + tid] = incl - v + carry;
        __syncthreads();
        if (tid == 0) carry_s = carry + total;
        __syncthreads();
    }
}

__global__ void __launch_bounds__(256) fixup_kernel(int* __restrict__ rowptr,
                                                    const int* __restrict__ bsum, int n,
                                                    int Etot, int* __restrict__ cursor)
{
    int i = blockIdx.x * 256 + threadIdx.x;
    const int stride = gridDim.x * 256;
    if (i == 0) rowptr[n] = Etot;
    for (; i < n; i += stride) {
        const int r = rowptr[i] + bsum[i >> 11];
        rowptr[i] = r; cursor[i] = r;
    }
}

// XCD-sharded placement: blocks with (blockIdx&7)==g handle dst-bins in shard g's
// contiguous range only -> that shard's cursor+csr slice (~1.9MB) stays resident in
// one XCD's L2 instead of thrashing across 8 (was: 151MB HBM writes for 9.6MB csr).
__global__ void __launch_bounds__(256) place_kernel(EdgeArgs ea, int Etot, int Nbins,
                                                    int* __restrict__ cursor,
                                                    int* __restrict__ csr)
{
    const int shard = blockIdx.x & 7;
    const int lo = (int)(((long long)shard * Nbins) >> 3);
    const int hi = (int)(((long long)(shard + 1) * Nbins) >> 3);
    int g = (blockIdx.x >> 3) * 256 + threadIdx.x;
    const int stride = (gridDim.x >> 3) * 256;
    for (; g < Etot; g += stride) {
        int t = 0;
        while (g >= ea.ebase[t + 1]) ++t;
        const int e = g - ea.ebase[t];
        const int dst = ea.ei[t][ea.E[t] + e];
        const int gb = ea.binbase[t] + dst;
        if (gb >= lo && gb < hi) {
            const int src = ea.ei[t][e];
            const int pos = atomicAdd(&cursor[gb], 1);
            csr[pos] = src;
        }
    }
}

// ---------------------------------------------------------------- gather64
// wave per dst row (high-degree rows, dst=global): 4 edges in flight.
__global__ void __launch_bounds__(256) gather64(const __bf16* __restrict__ x,
                                                const int* __restrict__ rowptr,
                                                const int* __restrict__ csr,
                                                __bf16* __restrict__ agg, int N)
{
    const int lane = threadIdx.x & 63;
    const int l16 = lane & 15, grp = lane >> 4;
    int wv = (blockIdx.x * 256 + threadIdx.x) >> 6;
    const int nwv = (gridDim.x * 256) >> 6;
    for (int row = wv; row < N; row += nwv) {
        const int p0 = rowptr[row], p1 = rowptr[row + 1];
        float acc[8] = {0.f, 0.f, 0.f, 0.f, 0.f, 0.f, 0.f, 0.f};
        for (int p = p0 + grp; p < p1; p += 4) {
            const int s = csr[p];
            const bf16x8 v = *reinterpret_cast<const bf16x8*>(x + (size_t)s * 128 + l16 * 8);
#pragma unroll
            for (int j = 0; j < 8; ++j) acc[j] += (float)v[j];
        }
#pragma unroll
        for (int j = 0; j < 8; ++j) {
            acc[j] += __shfl_xor(acc[j], 16);
            acc[j] += __shfl_xor(acc[j], 32);
        }
        if (grp == 0) {
            bf16x8 o;
#pragma unroll
            for (int j = 0; j < 8; ++j) o[j] = (__bf16)acc[j];
            *reinterpret_cast<bf16x8*>(agg + (size_t)row * 128 + l16 * 8) = o;
        }
    }
}

// ---------------------------------------------------------------- fused gather + GEMM + BN stats
// FUSED: block gathers its 128 rows into LDS (XOR-swizzled 16B blocks) then MFMAs from LDS.
// !FUSED: A (ks<4) read from pre-gathered agg in global (high-degree convs).
// h = [agg | x_dst](M,256) @ Wp(256,128) + bias ; stats += {colsum(h), colsum(h^2)}
template<bool FUSED>
__global__ void __launch_bounds__(256) fgemm(const __bf16* __restrict__ xsrc,
                                             const __bf16* __restrict__ agg,
                                             const int* __restrict__ rowptr,
                                             const int* __restrict__ csr,
                                             const __bf16* __restrict__ xdst,
                                             const __bf16* __restrict__ Wp,
                                             const float* __restrict__ bias,
                                             __bf16* __restrict__ hout,
                                             float* __restrict__ stats, int M)
{
    __shared__ __bf16 atile[128 * 128];   // 32 KB, used when FUSED
    __shared__ float lsum[128];
    __shared__ float lsq[128];
    const int tid  = threadIdx.x;
    const int lane = tid & 63;
    const int wv   = tid >> 6;
    if (tid < 128) { lsum[tid] = 0.f; lsq[tid] = 0.f; }

    const int r0 = blockIdx.x * 128;

    if (FUSED) {
        // gather phase: 16 groups of 16 lanes; group g owns local rows g*8..g*8+7
        const int grp = tid >> 4, l16 = tid & 15;
#pragma unroll
        for (int rr = 0; rr < 8; ++rr) {
            const int lr  = grp * 8 + rr;
            const int row = r0 + lr;
            float acc[8] = {0.f, 0.f, 0.f, 0.f, 0.f, 0.f, 0.f, 0.f};
            if (row < M) {
                const int p0 = rowptr[row], p1 = rowptr[row + 1];
                for (int p = p0; p < p1; ++p) {
                    const int s = csr[p];
                    const bf16x8 v = *reinterpret_cast<const bf16x8*>(
                        xsrc + (size_t)s * 128 + l16 * 8);
#pragma unroll
                    for (int j = 0; j < 8; ++j) acc[j] += (float)v[j];
                }
            }
            bf16x8 o;
#pragma unroll
            for (int j = 0; j < 8; ++j) o[j] = (__bf16)acc[j];
            // swizzle: 16B block index cb=l16 -> cb ^ (lr&7)
            char* dp = (char*)atile + lr * 256 + ((l16 * 16) ^ ((lr & 7) << 4));
            *reinterpret_cast<bf16x8*>(dp) = o;
        }
    }
    __syncthreads();

    const int lrow  = lane & 15;
    const int klane = (lane >> 4) * 8;

    int  car[2]; bool val[2];
#pragma unroll
    for (int rf = 0; rf < 2; ++rf) {
        const int ar = r0 + wv * 32 + rf * 16 + lrow;
        val[rf] = ar < M;
        car[rf] = val[rf] ? ar : (M - 1);
    }

    bf16x8 z8;
#pragma unroll
    for (int j = 0; j < 8; ++j) z8[j] = (__bf16)0.f;

    f32x4 acc[2][8];
#pragma unroll
    for (int rf = 0; rf < 2; ++rf)
#pragma unroll
        for (int cf = 0; cf < 8; ++cf) {
            f32x4 z; z[0] = 0.f; z[1] = 0.f; z[2] = 0.f; z[3] = 0.f;
            acc[rf][cf] = z;
        }

#pragma unroll
    for (int ks = 0; ks < 8; ++ks) {
        const int koff = (ks & 3) * 32 + klane;
        bf16x8 a[2];
#pragma unroll
        for (int rf = 0; rf < 2; ++rf) {
            if (ks < 4) {
                if (FUSED) {
                    const int lr = wv * 32 + rf * 16 + lrow;   // 0..127 local row
                    const char* sp = (const char*)atile + lr * 256
                                   + ((koff * 2) ^ ((lr & 7) << 4));
                    a[rf] = *reinterpret_cast<const bf16x8*>(sp);
                } else {
                    const bf16x8 av = *reinterpret_cast<const bf16x8*>(
                        agg + (size_t)car[rf] * 128 + koff);
                    a[rf] = val[rf] ? av : z8;
                }
            } else {
                const bf16x8 av = *reinterpret_cast<const bf16x8*>(
                    xdst + (size_t)car[rf] * 128 + koff);
                a[rf] = val[rf] ? av : z8;
            }
        }
        const bf16x8* wp8 = reinterpret_cast<const bf16x8*>(Wp) + (size_t)ks * 8 * 64 + lane;
        bf16x8 b[8];
#pragma unroll
        for (int cf = 0; cf < 8; ++cf) b[cf] = wp8[(size_t)cf * 64];
#pragma unroll
        for (int rf = 0; rf < 2; ++rf)
#pragma unroll
            for (int cf = 0; cf < 8; ++cf)
                acc[rf][cf] = __builtin_amdgcn_mfma_f32_16x16x32_bf16(a[rf], b[cf], acc[rf][cf], 0, 0, 0);
    }

    float bc[8];
#pragma unroll
    for (int cf = 0; cf < 8; ++cf) bc[cf] = bias[cf * 16 + lrow];

    const int rb = (lane >> 4) * 4;
#pragma unroll
    for (int cf = 0; cf < 8; ++cf) {
        float s = 0.f, q = 0.f;
#pragma unroll
        for (int rf = 0; rf < 2; ++rf) {
#pragma unroll
            for (int rr = 0; rr < 4; ++rr) {
                const int grow = r0 + wv * 32 + rf * 16 + rb + rr;
                if (grow < M) {
                    const float hv = acc[rf][cf][rr] + bc[cf];
                    hout[(size_t)grow * 128 + cf * 16 + lrow] = (__bf16)hv;
                    s += hv; q += hv * hv;
                }
            }
        }
        s += __shfl_xor(s, 16); s += __shfl_xor(s, 32);
        q += __shfl_xor(q, 16); q += __shfl_xor(q, 32);
        if (lane < 16) {
            atomicAdd(&lsum[cf * 16 + lane], s);
            atomicAdd(&lsq [cf * 16 + lane], q);
        }
    }
    __syncthreads();
    if (tid < 128) {
        atomicAdd(&stats[tid],       lsum[tid]);
        atomicAdd(&stats[128 + tid], lsq[tid]);
    }
}

// ---------------------------------------------------------------- normalize + accumulate
// BN prep folded in. MODE 0: out(bf16)=v ; 1: out(bf16)+=v ; 2: out(f32)+=v ; 3: out(f32)=resid+v
template<int MODE>
__global__ void __launch_bounds__(256) norm_kernel(const __bf16* __restrict__ h,
                                                   const float* __restrict__ stats,
                                                   const float* __restrict__ gamma,
                                                   const float* __restrict__ beta,
                                                   float invM,
                                                   const float* __restrict__ resid,
                                                   void* __restrict__ out, int M)
{
    __shared__ float ssc[128], ssh[128];
    const int tid = threadIdx.x;
    if (tid < 128) {
        const float mu   = stats[tid] * invM;
        const float var  = stats[128 + tid] * invM - mu * mu;
        const float scal = gamma[tid] * rsqrtf(var + 1e-5f);
        ssc[tid] = scal;
        ssh[tid] = beta[tid] - mu * scal;
    }
    __syncthreads();

    const int t0   = blockIdx.x * 256 + tid;
    const int nthr = gridDim.x * 256;
    const int c0   = (t0 & 15) * 8;
    float sc[8], sh[8];
#pragma unroll
    for (int j = 0; j < 8; ++j) { sc[j] = ssc[c0 + j]; sh[j] = ssh[c0 + j]; }
    const int nch = M * 16;
    for (int ch = t0; ch < nch; ch += nthr) {
        const bf16x8 hv = *reinterpret_cast<const bf16x8*>(h + (size_t)ch * 8);
        float f[8];
#pragma unroll
        for (int j = 0; j < 8; ++j) f[j] = (float)hv[j] * sc[j] + sh[j];
        if constexpr (MODE == 0) {
            bf16x8 ov;
#pragma unroll
            for (int j = 0; j < 8; ++j) ov[j] = (__bf16)f[j];
            *reinterpret_cast<bf16x8*>((__bf16*)out + (size_t)ch * 8) = ov;
        } else if constexpr (MODE == 1) {
            __bf16* op = (__bf16*)out + (size_t)ch * 8;
            bf16x8 ov = *reinterpret_cast<const bf16x8*>(op);
#pragma unroll
            for (int j = 0; j < 8; ++j) ov[j] = (__bf16)((float)ov[j] + f[j]);
            *reinterpret_cast<bf16x8*>(op) = ov;
        } else if constexpr (MODE == 2) {
            float* op = (float*)out + (size_t)ch * 8;
            float4 o0 = *reinterpret_cast<float4*>(op);
            float4 o1 = *reinterpret_cast<float4*>(op + 4);
            o0.x += f[0]; o0.y += f[1]; o0.z += f[2]; o0.w += f[3];
            o1.x += f[4]; o1.y += f[5]; o1.z += f[6]; o1.w += f[7];
            *reinterpret_cast<float4*>(op)     = o0;
            *reinterpret_cast<float4*>(op + 4) = o1;
        } else {
            const float* rp = resid + (size_t)ch * 8;
            const float4 r0 = *reinterpret_cast<const float4*>(rp);
            const float4 r1 = *reinterpret_cast<const float4*>(rp + 4);
            float* op = (float*)out + (size_t)ch * 8;
            float4 o0, o1;
            o0.x = r0.x + f[0]; o0.y = r0.y + f[1]; o0.z = r0.z + f[2]; o0.w = r0.w + f[3];
            o1.x = r1.x + f[4]; o1.y = r1.y + f[5]; o1.z = r1.z + f[6]; o1.w = r1.w + f[7];
            *reinterpret_cast<float4*>(op)     = o0;
            *reinterpret_cast<float4*>(op + 4) = o1;
        }
    }
}

// ---------------------------------------------------------------- launch
extern "C" void kernel_launch(void* const* d_in, const int* in_sizes, int n_in,
                              void* d_out, int out_size, void* d_ws, size_t ws_size,
                              hipStream_t stream)
{
    const float* xin[3] = {(const float*)d_in[0], (const float*)d_in[1], (const float*)d_in[2]};
    const int N[3] = {in_sizes[0] / 128, in_sizes[1] / 128, in_sizes[2] / 128};
    const float* Wrel  = (const float*)d_in[12];
    const float* brel  = (const float*)d_in[13];
    const float* Wroot = (const float*)d_in[14];
    const float* gamma = (const float*)d_in[15];
    const float* beta  = (const float*)d_in[16];

    // ETS order: a2b b2a a2g g2a b2g g2b a2a b2b g2g  (atom=0,bond=1,global=2)
    const int cs[9] = {0, 1, 0, 2, 1, 2, 0, 1, 2};
    const int cd[9] = {1, 0, 2, 0, 2, 1, 0, 1, 2};

    const size_t nA = (size_t)N[0] * 128, nB = (size_t)N[1] * 128, nG = (size_t)N[2] * 128;
    const size_t off[3] = {0, nA, nA + nB};
    const size_t xtot = nA + nB + nG;
    size_t maxN = (size_t)N[0];
    if ((size_t)N[1] > maxN) maxN = N[1];
    if ((size_t)N[2] > maxN) maxN = N[2];

    // edge/bin geometry
    EdgeArgs ea;
    int Etot = 0, Nbins = 0;
    ea.ebase[0] = 0;
    for (int t = 0; t < 9; ++t) {
        ea.ei[t] = (const int*)d_in[3 + t];
        ea.E[t]  = in_sizes[3 + t] / 2;
        ea.ebase[t + 1] = ea.ebase[t] + ea.E[t];
        ea.binbase[t] = Nbins;
        Nbins += N[cd[t]];
    }
    Etot = ea.ebase[9];
    const int nb1 = (Nbins + SCHUNK - 1) / SCHUNK;

    // ws layout
    auto al = [](size_t x) { return (x + 15) & ~(size_t)15; };
    char* w = (char*)d_ws;
    __bf16* x0b   = (__bf16*)w;  w += al(xtot * 2);
    __bf16* x1    = (__bf16*)w;  w += al(xtot * 2);
    __bf16* agg   = (__bf16*)w;  w += al(maxN * 128 * 2);
    __bf16* hbuf  = (__bf16*)w;  w += al(maxN * 128 * 2);
    float*  stats = (float*)w;   w += al(18 * 256 * 4);
    __bf16* Wp    = (__bf16*)w;  w += al((size_t)18 * 32768 * 2);
    int*    deg   = (int*)w;     w += al((size_t)Nbins * 4);
    int*    rowptr= (int*)w;     w += al(((size_t)Nbins + 1) * 4);
    int*    cursor= (int*)w;     w += al((size_t)Nbins * 4);
    int*    csr   = (int*)w;     w += al((size_t)Etot * 4);
    int*    bsum  = (int*)w;     w += al((size_t)nb1 * 4);
    (void)ws_size; (void)n_in; (void)out_size;

    pack_w<<<288, 256, 0, stream>>>(Wrel, Wroot, Wp);
    for (int k = 0; k < 3; ++k) {
        const int n8 = (int)(((k == 0 ? nA : k == 1 ? nB : nG)) / 8);
        int cb = (n8 + 255) / 256; if (cb > 2048) cb = 2048;
        cvt_kernel<<<cb, 256, 0, stream>>>(xin[k], x0b + off[k], n8);
    }
    hipMemsetAsync(deg, 0, (size_t)Nbins * 4, stream);
    hipMemsetAsync(stats, 0, 18 * 256 * 4, stream);

    int eb = (Etot + 255) / 256; if (eb > 2048) eb = 2048;
    hist_kernel<<<eb, 256, 0, stream>>>(ea, Etot, deg);
    scan1_kernel<<<nb1, 256, 0, stream>>>(deg, Nbins, rowptr, bsum);
    scan2_kernel<<<1, 256, 0, stream>>>(bsum, nb1);
    int fb = (Nbins + 255) / 256; if (fb > 2048) fb = 2048;
    fixup_kernel<<<fb, 256, 0, stream>>>(rowptr, bsum, Nbins, Etot, cursor);
    place_kernel<<<2048, 256, 0, stream>>>(ea, Etot, Nbins, cursor, csr);

    float* dout = (float*)d_out;

    for (int L = 0; L < 2; ++L) {
        const __bf16* xsrcbase = (L == 0) ? x0b : x1;
        for (int i = 0; i < 9; ++i) {
            const int s = cs[i], d = cd[i];
            const int E = ea.E[i];
            const int li = L * 9 + i;
            float* st = stats + li * 256;
            const int Nd = N[d];
            const int* rp = rowptr + ea.binbase[i];
            const int gb = (Nd + 127) / 128;

            if (E >= 8 * Nd) {  // high-degree rows (dst=global): wave-per-row gather, unfused
                int gb2 = (Nd * 64 + 255) / 256; if (gb2 > 2048) gb2 = 2048; if (gb2 < 1) gb2 = 1;
                gather64<<<gb2, 256, 0, stream>>>(xsrcbase + off[s], rp, csr, agg, Nd);
                fgemm<false><<<gb, 256, 0, stream>>>(xsrcbase + off[s], agg, rp, csr,
                    xsrcbase + off[d], Wp + (size_t)li * 32768, brel + li * 128, hbuf, st, Nd);
            } else {
                fgemm<true><<<gb, 256, 0, stream>>>(xsrcbase + off[s], agg, rp, csr,
                    xsrcbase + off[d], Wp + (size_t)li * 32768, brel + li * 128, hbuf, st, Nd);
            }

            const float invM = 1.0f / (float)Nd;
            const long long nch = (long long)Nd * 16;
            int nb = (int)((nch + 255) / 256); if (nb > 2048) nb = 2048;
            if (L == 0) {
                if (i < 3) norm_kernel<0><<<nb, 256, 0, stream>>>(hbuf, st, gamma + li * 128,
                               beta + li * 128, invM, nullptr, (void*)(x1 + off[d]), Nd);
                else       norm_kernel<1><<<nb, 256, 0, stream>>>(hbuf, st, gamma + li * 128,
                               beta + li * 128, invM, nullptr, (void*)(x1 + off[d]), Nd);
            } else {
                if (i < 3) norm_kernel<3><<<nb, 256, 0, stream>>>(hbuf, st, gamma + li * 128,
                               beta + li * 128, invM, xin[d], (void*)(dout + off[d]), Nd);
                else       norm_kernel<2><<<nb, 256, 0, stream>>>(hbuf, st, gamma + li * 128,
                               beta + li * 128, invM, nullptr, (void*)(dout + off[d]), Nd);
            }
        }
    }
}

// Round 8
// 1546.631 us; speedup vs baseline: 1.7735x; 1.4738x over previous
//
#include <hip/hip_runtime.h>
#include <hip/hip_bf16.h>

typedef __bf16 bf16x8 __attribute__((ext_vector_type(8)));
typedef float  f32x4  __attribute__((ext_vector_type(4)));

#define SCHUNK 2048  // elements per scan1 block (256 thr * 8)

struct EdgeArgs {
    const int* ei[9];
    int E[9];
    int ebase[10];   // prefix over edges
    int binbase[9];  // prefix over dst bins
};

struct ConvGroup {          // 3 convs sharing the same dst type
    const int* rowptr[3];
    const __bf16* xsrc[3];
    const __bf16* agg[3];   // pre-gathered A (unfused convs)
    const __bf16* Wp[3];
    const float* bias[3];
    float* stats[3];
    __bf16* hout[3];
    const __bf16* xdst;
    const int* csr;
    int fused[3];
    int M;
};

struct NormGroup {
    const __bf16* h[3];
    const float* stats[3];
    const float* gamma[3];
    const float* beta[3];
    const float* resid;     // f32 base (L1) or null
    void* out;
    float invM;
    int M;
};

// ---------------------------------------------------------------- pack W
// Layout: [li=L*9+i][ks(8)][cf(8)][lane(64)][j(8)]  (bf16)
// k = ks*32 + (lane>>4)*8 + j ; col = cf*16 + (lane&15)
__global__ void __launch_bounds__(256) pack_w(const float* __restrict__ Wrel,
                                              const float* __restrict__ Wroot,
                                              __bf16* __restrict__ Wp)
{
    const int idx = blockIdx.x * 256 + threadIdx.x;
    if (idx >= 2 * 9 * 8 * 8 * 64) return;
    const int lane = idx & 63;
    int t = idx >> 6;
    const int cf = t & 7; t >>= 3;
    const int ks = t & 7; t >>= 3;
    const int li = t;  // 0..17
    const int col = cf * 16 + (lane & 15);
    const int kb  = ks * 32 + (lane >> 4) * 8;
    bf16x8 o;
#pragma unroll
    for (int j = 0; j < 8; ++j) {
        const int k = kb + j;
        const float v = (k < 128)
            ? Wrel [((size_t)li * 128 + k)        * 128 + col]
            : Wroot[((size_t)li * 128 + (k - 128)) * 128 + col];
        o[j] = (__bf16)v;
    }
    *reinterpret_cast<bf16x8*>(Wp + (size_t)idx * 8) = o;
}

// ---------------------------------------------------------------- f32 -> bf16 convert
__global__ void __launch_bounds__(256) cvt_kernel(const float* __restrict__ in,
                                                  __bf16* __restrict__ out, int n8)
{
    int i = blockIdx.x * 256 + threadIdx.x;
    const int stride = gridDim.x * 256;
    for (; i < n8; i += stride) {
        const float4 f0 = *reinterpret_cast<const float4*>(in + (size_t)i * 8);
        const float4 f1 = *reinterpret_cast<const float4*>(in + (size_t)i * 8 + 4);
        bf16x8 o;
        o[0] = (__bf16)f0.x; o[1] = (__bf16)f0.y; o[2] = (__bf16)f0.z; o[3] = (__bf16)f0.w;
        o[4] = (__bf16)f1.x; o[5] = (__bf16)f1.y; o[6] = (__bf16)f1.z; o[7] = (__bf16)f1.w;
        *reinterpret_cast<bf16x8*>(out + (size_t)i * 8) = o;
    }
}

// ---------------------------------------------------------------- CSR build
__global__ void __launch_bounds__(256) hist_kernel(EdgeArgs ea, int Etot,
                                                   int* __restrict__ deg)
{
    int g = blockIdx.x * 256 + threadIdx.x;
    const int stride = gridDim.x * 256;
    for (; g < Etot; g += stride) {
        int t = 0;
        while (g >= ea.ebase[t + 1]) ++t;
        const int e = g - ea.ebase[t];
        const int dst = __builtin_nontemporal_load(&ea.ei[t][ea.E[t] + e]);
        atomicAdd(&deg[ea.binbase[t] + dst], 1);
    }
}

__global__ void __launch_bounds__(256) scan1_kernel(const int* __restrict__ deg, int n,
                                                    int* __restrict__ rowptr,
                                                    int* __restrict__ bsum)
{
    __shared__ int lds[256];
    const int tid = threadIdx.x;
    const int base = blockIdx.x * SCHUNK + tid * 8;
    int v[8]; int tsum = 0;
#pragma unroll
    for (int j = 0; j < 8; ++j) { v[j] = (base + j < n) ? deg[base + j] : 0; tsum += v[j]; }
    int incl = tsum;
    lds[tid] = incl; __syncthreads();
    for (int off = 1; off < 256; off <<= 1) {
        const int add = (tid >= off) ? lds[tid - off] : 0;
        __syncthreads();
        incl += add; lds[tid] = incl; __syncthreads();
    }
    if (tid == 255) bsum[blockIdx.x] = incl;
    int run = incl - tsum;
#pragma unroll
    for (int j = 0; j < 8; ++j) { if (base + j < n) rowptr[base + j] = run; run += v[j]; }
}

__global__ void __launch_bounds__(256) scan2_kernel(int* __restrict__ bsum, int nb)
{
    __shared__ int lds[256];
    __shared__ int carry_s;
    const int tid = threadIdx.x;
    if (tid == 0) carry_s = 0;
    __syncthreads();
    for (int base = 0; base < nb; base += 256) {
        const int v = (base + tid < nb) ? bsum[base + tid] : 0;
        int incl = v;
        lds[tid] = incl; __syncthreads();
        for (int off = 1; off < 256; off <<= 1) {
            const int add = (tid >= off) ? lds[tid - off] : 0;
            __syncthreads();
            incl += add; lds[tid] = incl; __syncthreads();
        }
        const int total = lds[255];
        const int carry = carry_s;
        if (base + tid < nb) bsum[base + tid] = incl - v + carry;
        __syncthreads();
        if (tid == 0) carry_s = carry + total;
        __syncthreads();
    }
}

__global__ void __launch_bounds__(256) fixup_kernel(int* __restrict__ rowptr,
                                                    const int* __restrict__ bsum, int n,
                                                    int Etot, int* __restrict__ cursor)
{
    int i = blockIdx.x * 256 + threadIdx.x;
    const int stride = gridDim.x * 256;
    if (i == 0) rowptr[n] = Etot;
    for (; i < n; i += stride) {
        const int r = rowptr[i] + bsum[i >> 11];
        rowptr[i] = r; cursor[i] = r;
    }
}

// XCD-sharded placement; nontemporal edge reads keep the streaming re-read from
// evicting the shard's dirty cursor/csr lines out of L2.
__global__ void __launch_bounds__(256) place_kernel(EdgeArgs ea, int Etot, int Nbins,
                                                    int* __restrict__ cursor,
                                                    int* __restrict__ csr)
{
    const int shard = blockIdx.x & 7;
    const int lo = (int)(((long long)shard * Nbins) >> 3);
    const int hi = (int)(((long long)(shard + 1) * Nbins) >> 3);
    int g = (blockIdx.x >> 3) * 256 + threadIdx.x;
    const int stride = (gridDim.x >> 3) * 256;
    for (; g < Etot; g += stride) {
        int t = 0;
        while (g >= ea.ebase[t + 1]) ++t;
        const int e = g - ea.ebase[t];
        const int dst = __builtin_nontemporal_load(&ea.ei[t][ea.E[t] + e]);
        const int gb = ea.binbase[t] + dst;
        if (gb >= lo && gb < hi) {
            const int src = __builtin_nontemporal_load(&ea.ei[t][e]);
            const int pos = atomicAdd(&cursor[gb], 1);
            csr[pos] = src;
        }
    }
}

// ---------------------------------------------------------------- gather64
// wave per dst row (high-degree rows, dst=global): pairwise loads, 8 in flight/wave.
__global__ void __launch_bounds__(256) gather64(const __bf16* __restrict__ x,
                                                const int* __restrict__ rowptr,
                                                const int* __restrict__ csr,
                                                __bf16* __restrict__ agg, int N)
{
    const int lane = threadIdx.x & 63;
    const int l16 = lane & 15, grp = lane >> 4;
    int wv = (blockIdx.x * 256 + threadIdx.x) >> 6;
    const int nwv = (gridDim.x * 256) >> 6;
    for (int row = wv; row < N; row += nwv) {
        const int p0 = rowptr[row], p1 = rowptr[row + 1];
        float acc[8] = {0.f, 0.f, 0.f, 0.f, 0.f, 0.f, 0.f, 0.f};
        int p = p0 + grp * 2;
        for (; p + 2 <= p1; p += 8) {
            const int s0 = csr[p], s1 = csr[p + 1];
            const bf16x8 v0 = *reinterpret_cast<const bf16x8*>(x + (size_t)s0 * 128 + l16 * 8);
            const bf16x8 v1 = *reinterpret_cast<const bf16x8*>(x + (size_t)s1 * 128 + l16 * 8);
#pragma unroll
            for (int j = 0; j < 8; ++j) acc[j] += (float)v0[j] + (float)v1[j];
        }
        if (p < p1) {
            const int s0 = csr[p];
            const bf16x8 v0 = *reinterpret_cast<const bf16x8*>(x + (size_t)s0 * 128 + l16 * 8);
#pragma unroll
            for (int j = 0; j < 8; ++j) acc[j] += (float)v0[j];
        }
#pragma unroll
        for (int j = 0; j < 8; ++j) {
            acc[j] += __shfl_xor(acc[j], 16);
            acc[j] += __shfl_xor(acc[j], 32);
        }
        if (grp == 0) {
            bf16x8 o;
#pragma unroll
            for (int j = 0; j < 8; ++j) o[j] = (__bf16)acc[j];
            *reinterpret_cast<bf16x8*>(agg + (size_t)row * 128 + l16 * 8) = o;
        }
    }
}

// ---------------------------------------------------------------- batched fused gather+GEMM+stats
// grid.y = conv j in dst-group. fused[j]: gather 128 rows into XOR-swizzled LDS then MFMA;
// else A(ks<4) from pre-gathered agg[j]. xdst fragments register-preloaded before gather
// so HBM latency hides under the gather chain.
__global__ void __launch_bounds__(256, 3) fgemm_group(ConvGroup cg)
{
    __shared__ __bf16 atile[128 * 128];   // 32 KB
    __shared__ float lsum[128];
    __shared__ float lsq[128];
    const int cj   = blockIdx.y;
    const int M    = cg.M;
    const int tid  = threadIdx.x;
    const int lane = tid & 63;
    const int wv   = tid >> 6;
    if (tid < 128) { lsum[tid] = 0.f; lsq[tid] = 0.f; }

    const int r0 = blockIdx.x * 128;
    const int lrow  = lane & 15;
    const int klane = (lane >> 4) * 8;

    int  car[2]; bool val[2];
#pragma unroll
    for (int rf = 0; rf < 2; ++rf) {
        const int ar = r0 + wv * 32 + rf * 16 + lrow;
        val[rf] = ar < M;
        car[rf] = val[rf] ? ar : (M - 1);
    }
    bf16x8 z8;
#pragma unroll
    for (int j = 0; j < 8; ++j) z8[j] = (__bf16)0.f;

    // early xdst fragment loads (k=128..255 half of A) — overlap with gather
    bf16x8 xd[2][4];
#pragma unroll
    for (int rf = 0; rf < 2; ++rf)
#pragma unroll
        for (int kk = 0; kk < 4; ++kk) {
            const bf16x8 av = *reinterpret_cast<const bf16x8*>(
                cg.xdst + (size_t)car[rf] * 128 + kk * 32 + klane);
            xd[rf][kk] = val[rf] ? av : z8;
        }

    const bool fused = cg.fused[cj] != 0;
    if (fused) {
        const int* __restrict__ rp  = cg.rowptr[cj];
        const int* __restrict__ csr = cg.csr;
        const __bf16* __restrict__ xsrc = cg.xsrc[cj];
        const int grp = tid >> 4, l16 = tid & 15;
        int pr[9];
#pragma unroll
        for (int rr = 0; rr < 9; ++rr) {
            int rw = r0 + grp * 8 + rr;
            pr[rr] = rp[rw > M ? M : rw];   // rows >= M collapse to empty ranges
        }
#pragma unroll
        for (int rr = 0; rr < 8; ++rr) {
            const int lr = grp * 8 + rr;
            const int p1 = pr[rr + 1];
            float acc[8] = {0.f, 0.f, 0.f, 0.f, 0.f, 0.f, 0.f, 0.f};
            int p = pr[rr];
            for (; p + 2 <= p1; p += 2) {       // pairwise: 2 csr + 2 x loads in flight
                const int s0 = csr[p], s1 = csr[p + 1];
                const bf16x8 v0 = *reinterpret_cast<const bf16x8*>(
                    xsrc + (size_t)s0 * 128 + l16 * 8);
                const bf16x8 v1 = *reinterpret_cast<const bf16x8*>(
                    xsrc + (size_t)s1 * 128 + l16 * 8);
#pragma unroll
                for (int j = 0; j < 8; ++j) acc[j] += (float)v0[j] + (float)v1[j];
            }
            if (p < p1) {
                const int s0 = csr[p];
                const bf16x8 v0 = *reinterpret_cast<const bf16x8*>(
                    xsrc + (size_t)s0 * 128 + l16 * 8);
#pragma unroll
                for (int j = 0; j < 8; ++j) acc[j] += (float)v0[j];
            }
            bf16x8 o;
#pragma unroll
            for (int j = 0; j < 8; ++j) o[j] = (__bf16)acc[j];
            char* dp = (char*)atile + lr * 256 + ((l16 * 16) ^ ((lr & 7) << 4));
            *reinterpret_cast<bf16x8*>(dp) = o;
        }
    }
    __syncthreads();

    f32x4 acc[2][8];
#pragma unroll
    for (int rf = 0; rf < 2; ++rf)
#pragma unroll
        for (int cf = 0; cf < 8; ++cf) {
            f32x4 z; z[0] = 0.f; z[1] = 0.f; z[2] = 0.f; z[3] = 0.f;
            acc[rf][cf] = z;
        }

    const __bf16* __restrict__ aggp = cg.agg[cj];
    const __bf16* __restrict__ Wp   = cg.Wp[cj];
#pragma unroll
    for (int ks = 0; ks < 8; ++ks) {
        const int koff = (ks & 3) * 32 + klane;
        bf16x8 a[2];
#pragma unroll
        for (int rf = 0; rf < 2; ++rf) {
            if (ks < 4) {
                if (fused) {
                    const int lr = wv * 32 + rf * 16 + lrow;
                    const char* sp = (const char*)atile + lr * 256
                                   + ((koff * 2) ^ ((lr & 7) << 4));
                    a[rf] = *reinterpret_cast<const bf16x8*>(sp);
                } else {
                    const bf16x8 av = *reinterpret_cast<const bf16x8*>(
                        aggp + (size_t)car[rf] * 128 + koff);
                    a[rf] = val[rf] ? av : z8;
                }
            } else {
                a[rf] = xd[rf][ks - 4];
            }
        }
        const bf16x8* wp8 = reinterpret_cast<const bf16x8*>(Wp) + (size_t)ks * 8 * 64 + lane;
        bf16x8 b[8];
#pragma unroll
        for (int cf = 0; cf < 8; ++cf) b[cf] = wp8[(size_t)cf * 64];
#pragma unroll
        for (int rf = 0; rf < 2; ++rf)
#pragma unroll
            for (int cf = 0; cf < 8; ++cf)
                acc[rf][cf] = __builtin_amdgcn_mfma_f32_16x16x32_bf16(a[rf], b[cf], acc[rf][cf], 0, 0, 0);
    }

    const float* __restrict__ bias = cg.bias[cj];
    __bf16* __restrict__ hout = cg.hout[cj];
    float bc[8];
#pragma unroll
    for (int cf = 0; cf < 8; ++cf) bc[cf] = bias[cf * 16 + lrow];

    const int rb = (lane >> 4) * 4;
#pragma unroll
    for (int cf = 0; cf < 8; ++cf) {
        float s = 0.f, q = 0.f;
#pragma unroll
        for (int rf = 0; rf < 2; ++rf) {
#pragma unroll
            for (int rr = 0; rr < 4; ++rr) {
                const int grow = r0 + wv * 32 + rf * 16 + rb + rr;
                if (grow < M) {
                    const float hv = acc[rf][cf][rr] + bc[cf];
                    hout[(size_t)grow * 128 + cf * 16 + lrow] = (__bf16)hv;
                    s += hv; q += hv * hv;
                }
            }
        }
        s += __shfl_xor(s, 16); s += __shfl_xor(s, 32);
        q += __shfl_xor(q, 16); q += __shfl_xor(q, 32);
        if (lane < 16) {
            atomicAdd(&lsum[cf * 16 + lane], s);
            atomicAdd(&lsq [cf * 16 + lane], q);
        }
    }
    __syncthreads();
    float* __restrict__ st = cg.stats[cj];
    if (tid < 128) {
        atomicAdd(&st[tid],       lsum[tid]);
        atomicAdd(&st[128 + tid], lsq[tid]);
    }
}

// ---------------------------------------------------------------- batched normalize + sum 3 convs
// out = base + sum_j gamma_j*(h_j-mu_j)*rsqrt(var_j+eps)+beta_j ; base = 0 (L0/bf16) or resid (L1/f32)
template<bool F32OUT>
__global__ void __launch_bounds__(256) norm_group(NormGroup ng)
{
    __shared__ float ssc[3][128], ssh[3][128];
    const int tid = threadIdx.x;
    if (tid < 128) {
#pragma unroll
        for (int j = 0; j < 3; ++j) {
            const float mu   = ng.stats[j][tid] * ng.invM;
            const float var  = ng.stats[j][128 + tid] * ng.invM - mu * mu;
            const float scal = ng.gamma[j][tid] * rsqrtf(var + 1e-5f);
            ssc[j][tid] = scal;
            ssh[j][tid] = ng.beta[j][tid] - mu * scal;
        }
    }
    __syncthreads();

    const int t0   = blockIdx.x * 256 + tid;
    const int nthr = gridDim.x * 256;
    const int c0   = (t0 & 15) * 8;
    float sc[3][8], sh[3][8];
#pragma unroll
    for (int j = 0; j < 3; ++j)
#pragma unroll
        for (int k = 0; k < 8; ++k) { sc[j][k] = ssc[j][c0 + k]; sh[j][k] = ssh[j][c0 + k]; }

    const int nch = ng.M * 16;
    for (int ch = t0; ch < nch; ch += nthr) {
        float f[8] = {0.f, 0.f, 0.f, 0.f, 0.f, 0.f, 0.f, 0.f};
#pragma unroll
        for (int j = 0; j < 3; ++j) {
            const bf16x8 hv = *reinterpret_cast<const bf16x8*>(ng.h[j] + (size_t)ch * 8);
#pragma unroll
            for (int k = 0; k < 8; ++k) f[k] += (float)hv[k] * sc[j][k] + sh[j][k];
        }
        if constexpr (F32OUT) {
            const float* rp = ng.resid + (size_t)ch * 8;
            const float4 r0 = *reinterpret_cast<const float4*>(rp);
            const float4 r1 = *reinterpret_cast<const float4*>(rp + 4);
            float* op = (float*)ng.out + (size_t)ch * 8;
            float4 o0, o1;
            o0.x = r0.x + f[0]; o0.y = r0.y + f[1]; o0.z = r0.z + f[2]; o0.w = r0.w + f[3];
            o1.x = r1.x + f[4]; o1.y = r1.y + f[5]; o1.z = r1.z + f[6]; o1.w = r1.w + f[7];
            *reinterpret_cast<float4*>(op)     = o0;
            *reinterpret_cast<float4*>(op + 4) = o1;
        } else {
            bf16x8 ov;
#pragma unroll
            for (int k = 0; k < 8; ++k) ov[k] = (__bf16)f[k];
            *reinterpret_cast<bf16x8*>((__bf16*)ng.out + (size_t)ch * 8) = ov;
        }
    }
}

// ---------------------------------------------------------------- launch
extern "C" void kernel_launch(void* const* d_in, const int* in_sizes, int n_in,
                              void* d_out, int out_size, void* d_ws, size_t ws_size,
                              hipStream_t stream)
{
    const float* xin[3] = {(const float*)d_in[0], (const float*)d_in[1], (const float*)d_in[2]};
    const int N[3] = {in_sizes[0] / 128, in_sizes[1] / 128, in_sizes[2] / 128};
    const float* Wrel  = (const float*)d_in[12];
    const float* brel  = (const float*)d_in[13];
    const float* Wroot = (const float*)d_in[14];
    const float* gamma = (const float*)d_in[15];
    const float* beta  = (const float*)d_in[16];

    // ETS order: a2b b2a a2g g2a b2g g2b a2a b2b g2g  (atom=0,bond=1,global=2)
    const int cs[9] = {0, 1, 0, 2, 1, 2, 0, 1, 2};
    const int cd[9] = {1, 0, 2, 0, 2, 1, 0, 1, 2};
    // dst-groups: convs (ETS idx) per dst type
    const int gconv[3][3] = {{1, 3, 6},   // dst=atom : b2a, g2a, a2a
                             {0, 5, 7},   // dst=bond : a2b, g2b, b2b
                             {2, 4, 8}};  // dst=global: a2g, b2g, g2g

    const size_t nA = (size_t)N[0] * 128, nB = (size_t)N[1] * 128, nG = (size_t)N[2] * 128;
    const size_t off[3] = {0, nA, nA + nB};
    const size_t xtot = nA + nB + nG;
    size_t maxN = (size_t)N[0];
    if ((size_t)N[1] > maxN) maxN = N[1];
    if ((size_t)N[2] > maxN) maxN = N[2];

    // edge/bin geometry
    EdgeArgs ea;
    int Etot = 0, Nbins = 0;
    ea.ebase[0] = 0;
    for (int t = 0; t < 9; ++t) {
        ea.ei[t] = (const int*)d_in[3 + t];
        ea.E[t]  = in_sizes[3 + t] / 2;
        ea.ebase[t + 1] = ea.ebase[t] + ea.E[t];
        ea.binbase[t] = Nbins;
        Nbins += N[cd[t]];
    }
    Etot = ea.ebase[9];
    const int nb1 = (Nbins + SCHUNK - 1) / SCHUNK;

    // ws layout (~400 MB)
    auto al = [](size_t x) { return (x + 15) & ~(size_t)15; };
    char* w = (char*)d_ws;
    __bf16* x0b   = (__bf16*)w;  w += al(xtot * 2);
    __bf16* x1    = (__bf16*)w;  w += al(xtot * 2);
    __bf16* aggb  = (__bf16*)w;  w += al(2 * maxN * 128 * 2);
    __bf16* hbuf  = (__bf16*)w;  w += al(3 * maxN * 128 * 2);
    float*  stats = (float*)w;   w += al(18 * 256 * 4);
    __bf16* Wp    = (__bf16*)w;  w += al((size_t)18 * 32768 * 2);
    int*    deg   = (int*)w;     w += al((size_t)Nbins * 4);
    int*    rowptr= (int*)w;     w += al(((size_t)Nbins + 1) * 4);
    int*    cursor= (int*)w;     w += al((size_t)Nbins * 4);
    int*    csr   = (int*)w;     w += al((size_t)Etot * 4);
    int*    bsum  = (int*)w;     w += al((size_t)nb1 * 4);
    (void)ws_size; (void)n_in; (void)out_size;

    pack_w<<<288, 256, 0, stream>>>(Wrel, Wroot, Wp);
    for (int k = 0; k < 3; ++k) {
        const int n8 = (int)(((k == 0 ? nA : k == 1 ? nB : nG)) / 8);
        int cb = (n8 + 255) / 256; if (cb > 2048) cb = 2048;
        cvt_kernel<<<cb, 256, 0, stream>>>(xin[k], x0b + off[k], n8);
    }
    hipMemsetAsync(deg, 0, (size_t)Nbins * 4, stream);
    hipMemsetAsync(stats, 0, 18 * 256 * 4, stream);

    int eb = (Etot + 255) / 256; if (eb > 2048) eb = 2048;
    hist_kernel<<<eb, 256, 0, stream>>>(ea, Etot, deg);
    scan1_kernel<<<nb1, 256, 0, stream>>>(deg, Nbins, rowptr, bsum);
    scan2_kernel<<<1, 256, 0, stream>>>(bsum, nb1);
    int fb = (Nbins + 255) / 256; if (fb > 2048) fb = 2048;
    fixup_kernel<<<fb, 256, 0, stream>>>(rowptr, bsum, Nbins, Etot, cursor);
    place_kernel<<<2048, 256, 0, stream>>>(ea, Etot, Nbins, cursor, csr);

    float* dout = (float*)d_out;

    for (int L = 0; L < 2; ++L) {
        const __bf16* xb = (L == 0) ? x0b : x1;

        // pre-gather high-degree (deg>=8) convs: a2g (ets 2), b2g (ets 4)
        {
            const int Ng = N[2];
            int gb2 = (Ng * 64 + 255) / 256; if (gb2 > 2048) gb2 = 2048; if (gb2 < 1) gb2 = 1;
            gather64<<<gb2, 256, 0, stream>>>(xb + off[0], rowptr + ea.binbase[2], csr,
                                              aggb, Ng);
            gather64<<<gb2, 256, 0, stream>>>(xb + off[1], rowptr + ea.binbase[4], csr,
                                              aggb + maxN * 128, Ng);
        }

        for (int g = 0; g < 3; ++g) {
            const int d  = g;           // dst type == group index
            const int Nd = N[d];
            ConvGroup cg;
            NormGroup ng;
            cg.xdst = xb + off[d];
            cg.csr  = csr;
            cg.M    = Nd;
            for (int j = 0; j < 3; ++j) {
                const int et = gconv[g][j];
                const int li = L * 9 + et;
                cg.rowptr[j] = rowptr + ea.binbase[et];
                cg.xsrc[j]   = xb + off[cs[et]];
                cg.Wp[j]     = Wp + (size_t)li * 32768;
                cg.bias[j]   = brel + li * 128;
                cg.stats[j]  = stats + li * 256;
                cg.hout[j]   = hbuf + (size_t)j * maxN * 128;
                const bool hi = (et == 2) || (et == 4);
                cg.fused[j]  = hi ? 0 : 1;
                cg.agg[j]    = (et == 2) ? aggb : (et == 4 ? aggb + maxN * 128 : (const __bf16*)nullptr);
                ng.h[j]      = cg.hout[j];
                ng.stats[j]  = cg.stats[j];
                ng.gamma[j]  = gamma + li * 128;
                ng.beta[j]   = beta + li * 128;
            }
            const int gb = (Nd + 127) / 128;
            fgemm_group<<<dim3(gb, 3), 256, 0, stream>>>(cg);

            ng.invM = 1.0f / (float)Nd;
            ng.M    = Nd;
            const long long nch = (long long)Nd * 16;
            int nb = (int)((nch + 255) / 256); if (nb > 2048) nb = 2048;
            if (L == 0) {
                ng.resid = nullptr;
                ng.out   = (void*)(x1 + off[d]);
                norm_group<false><<<nb, 256, 0, stream>>>(ng);
            } else {
                ng.resid = xin[d];
                ng.out   = (void*)(dout + off[d]);
                norm_group<true><<<nb, 256, 0, stream>>>(ng);
            }
        }
    }
}